// Round 5
// baseline (47.958 us; speedup 1.0000x reference)
//
#include <hip/hip_runtime.h>

// LocalConv: out[b][o][oh][ow] = sum_f patch[p][b][f] * W[p][f][o]
// B=64, C=16, H=W=64, K=3x3, OH=OW=62, OUT_CH=32, FEAT=144, P=3844
//
// Round 5: barrier-free main loop. A-slab (inputs) staged once in LDS;
// weights stream global->VGPR per wave (32x32x16 MFMA, 9 exact K-chunks of
// 16 = c, chunk g = kh*3+kw). 4-deep chunk ring hides load latency. Wave =
// (mt half-batch, 2 consecutive positions). One __syncthreads total.
#define CIN    16
#define HH     64
#define WW     64
#define OHD    62
#define OWD    62
#define OUTC   32
#define FEATN  144
#define POUT   (OHD*OWD)
#define AR_W   10                      // slab w-dim (max TW+2)
#define AR_ELEMS (3*AR_W*64*16)        // 30720 ushort = 61440 B

typedef __attribute__((ext_vector_type(8)))  short short8;
typedef __attribute__((ext_vector_type(16))) float f32x16;
typedef __attribute__((ext_vector_type(2)))  float f32x2;

__device__ __forceinline__ unsigned short f2bf(float f) {
    unsigned int u = __float_as_uint(f);
    u += 0x7FFFu + ((u >> 16) & 1u);   // RNE
    return (unsigned short)(u >> 16);
}

template<int TW>
__device__ __forceinline__ void conv_body(
    const float* __restrict__ inp, const float* __restrict__ wgt,
    float* __restrict__ out, int oh, int ow0,
    unsigned short* __restrict__ Araw)
{
    const int tid = threadIdx.x;
    constexpr int WTOT = TW + 2;

    // ---- per-thread ids
    const int lane = tid & 63, wid = tid >> 6;
    const int o  = lane & 31;          // out channel
    const int hi = lane >> 5;          // k-half (and c-half)
    const int mt = wid & 1;            // batch half-tile (32 rows)
    const int q0 = (wid >> 1) * 2;     // first of this wave's 2 positions
    const int bA = mt * 32 + (lane & 31);                       // A row = batch
    const unsigned lbA = (unsigned)(2 * bA + hi) ^ ((unsigned)(bA >> 2) & 1u);

    // ---- weight ring: chunk t (t=0..17): pos q = q0 + t/9, g = t%9.
    //      base = wgt + p*4608 + (72*hi + g)*32 + o ; 8 loads at j*288.
    const float* wbase = wgt + (size_t)(oh * OWD + ow0 + q0) * (FEATN * OUTC)
                             + (72 * hi) * 32 + o;
    float ring[4][8];
    auto issue = [&](int t) {   // t compile-time under full unroll
        const float* p = wbase + (t / 9) * (FEATN * OUTC) + (t % 9) * 32;
        #pragma unroll
        for (int j = 0; j < 8; ++j) ring[t & 3][j] = p[j * 288];
    };

    const bool active = (q0 < TW);   // TW=6: wave qq=3 stages only

    // ---- prologue: prefetch 4 chunks (independent of LDS)
    if (active) { issue(0); issue(1); issue(2); issue(3); }

    // ---- stage A slab: Araw granule = (kh*AR_W+w)*128 + ((2b+s)^xb^wx)
    //      xb=(b>>2)&1 spreads frag-read banks; wx=(w&3)<<1 spreads writes
    for (int t = tid; t < 3 * WTOT * 64; t += 512) {
        int w   = t % WTOT;
        int rem = t / WTOT;
        int b   = rem & 63;
        int kh  = rem >> 6;
        const float* src = inp + (size_t)b * (CIN * HH * WW)
                               + (size_t)(oh + kh) * WW + (ow0 + w);
        short8 h0, h1;
        #pragma unroll
        for (int c = 0; c < 8; ++c) h0[c] = (short)f2bf(src[c * (HH * WW)]);
        #pragma unroll
        for (int c = 0; c < 8; ++c) h1[c] = (short)f2bf(src[(c + 8) * (HH * WW)]);
        unsigned g0 = (unsigned)(2 * b) ^ ((unsigned)(b >> 2) & 1u)
                                        ^ (unsigned)((w & 3) << 1);
        unsigned rb = (unsigned)(kh * AR_W + w) * 128u;
        *(short8*)(Araw + (size_t)(rb + g0)        * 8) = h0;  // c 0..7
        *(short8*)(Araw + (size_t)(rb + (g0 ^ 1u)) * 8) = h1;  // c 8..15
    }

    __syncthreads();   // the only barrier; slab is read-only afterwards

    f32x16 accA = {}, accB = {};

    if (active) {
        #pragma unroll
        for (int t = 0; t < 18; ++t) {
            constexpr int dummy = 0; (void)dummy;
            const int g  = t % 9;
            const int kh = g / 3, kw = g % 3;
            const int q  = q0 + t / 9;
            const int w  = q + kw;                 // <= TW+1 = WTOT-1
            // A fragment: row=bA, k=16g + 8hi + j  -> slab (kh, w, bA, c-half hi)
            unsigned off = (unsigned)((kh * AR_W + w) * 128)
                         + (lbA ^ (unsigned)((w & 3) << 1));
            short8 av = *(const short8*)(Araw + (size_t)off * 8);
            // B fragment: col=o, same k -> ring chunk t
            short8 bv;
            #pragma unroll
            for (int j = 0; j < 8; ++j) bv[j] = (short)f2bf(ring[t & 3][j]);
            if (t < 9)
                accA = __builtin_amdgcn_mfma_f32_32x32x16_bf16(av, bv, accA, 0, 0, 0);
            else
                accB = __builtin_amdgcn_mfma_f32_32x32x16_bf16(av, bv, accB, 0, 0, 0);
            if (t + 4 < 18) issue(t + 4);
        }

        // ---- stores: lane owns (b = mt*32 + row(r,hi), o), positions q0,q0+1
        //      row = (r&3) + 8*(r>>2) + 4*hi   [verified 32x32 C/D layout]
        #pragma unroll
        for (int r = 0; r < 16; ++r) {
            int row = (r & 3) + 8 * (r >> 2) + 4 * hi;
            float* dst = out + ((size_t)((mt * 32 + row) * OUTC + o)) * POUT
                             + (size_t)oh * OWD + (ow0 + q0);
            f32x2 v = { accA[r], accB[r] };
            *(f32x2*)dst = v;
        }
    }
}

__global__ __launch_bounds__(512, 4) void localconv_kernel(
    const float* __restrict__ inp,
    const float* __restrict__ wgt,
    float* __restrict__ out)
{
    __shared__ unsigned short Araw[AR_ELEMS];   // 61440 B -> 2 blocks/CU

    // chunked XCD swizzle: 496 = 8*62; XCD x gets contiguous l in [62x, 62x+62)
    const int l     = (blockIdx.x & 7) * 62 + (blockIdx.x >> 3);
    const int oh    = l >> 3;
    const int strip = l & 7;

    if (strip < 7) conv_body<8>(inp, wgt, out, oh, strip * 8, Araw);
    else           conv_body<6>(inp, wgt, out, oh, 56, Araw);
}

extern "C" void kernel_launch(void* const* d_in, const int* in_sizes, int n_in,
                              void* d_out, int out_size, void* d_ws, size_t ws_size,
                              hipStream_t stream) {
    const float* inp = (const float*)d_in[0];
    const float* wgt = (const float*)d_in[1];
    float* out = (float*)d_out;
    localconv_kernel<<<dim3(62 * 8), 512, 0, stream>>>(inp, wgt, out);
}

// Round 6
// 40.501 us; speedup vs baseline: 1.1841x; 1.1841x over previous
//
#include <hip/hip_runtime.h>

// LocalConv: out[b][o][oh][ow] = sum_f patch[p][b][f] * W[p][f][o]
// B=64, C=16, H=W=64, K=3x3, OH=OW=62, OUT_CH=32, FEAT=144, P=3844
// Round 6: TW=6 strips, 512 thr, LDS 68.6KB -> 2 blocks/CU (16 waves).
// Balanced 9-load/thread weight staging, depth-3 register pipeline.
// K permuted: f'' = (kh*3+kw)*16 + c.
#define CIN    16
#define HH     64
#define WW     64
#define OHD    62
#define OWD    62
#define OUTC   32
#define FEATN  144
#define POUT   (OHD*OWD)
#define LSTRB  152                      // B row stride: 144 real + 8 zero pad
#define AR_W   8                        // A slab w-dim (max TW+2)
#define AR_ELEMS   (3*AR_W*64*16)       // 24576 elems = 49152 B
#define BBUF_ELEMS (OUTC*LSTRB + 8)     // 4872 (last 8 = zero guard)
#define SMEM_BYTES ((AR_ELEMS + 2*BBUF_ELEMS)*2)   // 68640 B

typedef __attribute__((ext_vector_type(8))) short  short8;
typedef __attribute__((ext_vector_type(4))) float  f32x4;
typedef __attribute__((ext_vector_type(2))) float  f32x2;

__device__ __forceinline__ unsigned short f2bf(float f) {
    unsigned int u = __float_as_uint(f);
    u += 0x7FFFu + ((u >> 16) & 1u);   // RNE
    return (unsigned short)(u >> 16);
}

template<int TW>
__device__ __forceinline__ void conv_body(
    const float* __restrict__ inp, const float* __restrict__ wgt,
    float* __restrict__ out, int oh, int ow0,
    unsigned short* __restrict__ Araw, unsigned short* __restrict__ B_lds)
{
    const int tid = threadIdx.x;
    constexpr int WTOT = TW + 2;

    // ---- weight pipeline: thread = (o_w = tid&31, c_w = tid>>5 in 0..15).
    //      Exactly 9 scalar loads/thread/position: f = c_w*9 + g, g=0..8.
    //      Each wave-instr = 2 dense 128B lines. Depth-3 register ring.
    const int o_w = tid & 31;
    const int c_w = tid >> 5;
    const int p0  = oh * OWD + ow0;
    const float* wbase = wgt + (size_t)p0 * (FEATN * OUTC) + c_w * 288 + o_w;
    float ring[3][9];
    auto issue = [&](int t) {            // t compile-time under full unroll
        const float* p = wbase + (size_t)t * (FEATN * OUTC);
        #pragma unroll
        for (int g = 0; g < 9; ++g) ring[t % 3][g] = p[g * 32];
    };
    const int wb_base = o_w * LSTRB + c_w;     // + g*16
    auto writeB = [&](int t, unsigned short* Bb) {
        #pragma unroll
        for (int g = 0; g < 9; ++g)
            Bb[wb_base + g * 16] = f2bf(ring[t % 3][g]);
    };

    // ---- prologue loads first (independent of LDS staging below)
    issue(0);
    if (1 < TW) issue(1);
    if (2 < TW) issue(2);

    // ---- stage A slab: Araw granule G = ((kh*AR_W+w)*64+b)*2 + gr, swizzled
    //      gr = half ^ ((b>>2)&1); G ^= (w&3)<<1  (spreads write banks)
    for (int t = tid; t < 3 * WTOT * 64; t += 512) {
        int w   = t % WTOT;
        int rem = t / WTOT;
        int b   = rem & 63;
        int kh  = rem >> 6;
        const float* src = inp + (size_t)b * (CIN * HH * WW)
                               + (size_t)(oh + kh) * WW + (ow0 + w);
        short8 h0, h1;
        #pragma unroll
        for (int c = 0; c < 8; ++c) h0[c] = (short)f2bf(src[c * (HH * WW)]);
        #pragma unroll
        for (int c = 0; c < 8; ++c) h1[c] = (short)f2bf(src[(c + 8) * (HH * WW)]);
        int s = (b >> 2) & 1;
        unsigned Gb = (unsigned)(((kh * AR_W + w) * 64 + b) * 2);
        unsigned wx = (unsigned)((w & 3) << 1);
        *(short8*)(Araw + (((Gb + s) ^ wx) << 3))       = h0;
        *(short8*)(Araw + (((Gb + (1 - s)) ^ wx) << 3)) = h1;
    }

    // ---- zero B pad [144,152) per row + 8-elem guard, both buffers
    for (int t = tid; t < 2 * 264; t += 512) {
        int buf = t / 264, r = t % 264;
        int e = (r < 256) ? ((r >> 3) * LSTRB + 144 + (r & 7))
                          : (OUTC * LSTRB + (r & 7));
        B_lds[buf * BBUF_ELEMS + e] = 0;
    }

    writeB(0, B_lds);          // buf0 <- q0 (waits vmcnt via reg dep)

    // ---- fragment addressing (r4-verified)
    const int wid = tid >> 6, lane = tid & 63;
    const int fr = lane & 15, fq = lane >> 4, fqh = fq >> 1;
    const int mt = wid >> 1, nt = wid & 1;           // 4 m-tiles x 2 n-tiles
    const int b  = mt * 16 + fr;
    const int gr = (fq & 1) ^ ((b >> 2) & 1);
    unsigned abase_g[5]; int kwv[5]; int boff[5];
    #pragma unroll
    for (int kc = 0; kc < 5; ++kc) {
        int g  = 2 * kc + fqh;                 // 9 -> pad (zero A-frag)
        int gc = (g > 8) ? 8 : g;
        int kh = (gc * 11) >> 5;               // gc/3
        int kw = gc - 3 * kh;
        abase_g[kc] = (unsigned)(((kh * AR_W + kw) * 64 + b) * 2 + gr);
        kwv[kc]     = kw;
        boff[kc]    = (nt * 16 + fr) * LSTRB + kc * 32 + fq * 8;
    }

    __syncthreads();

    f32x4 acc[TW];
    #pragma unroll
    for (int q = 0; q < TW; ++q) acc[q] = (f32x4){0.f, 0.f, 0.f, 0.f};

    // ---- main loop: MFMA(q) | issue(q+3) | writeB(q+1) | barrier
    #pragma unroll
    for (int q = 0; q < TW; ++q) {
        const unsigned short* Bc = B_lds + (q & 1) * BBUF_ELEMS;
        #pragma unroll
        for (int kc = 0; kc < 5; ++kc) {
            short8 a;
            if (kc == 4 && fqh == 1) {
                a = (short8){0, 0, 0, 0, 0, 0, 0, 0};   // K in [144,160): A=0
            } else {
                unsigned gi = (abase_g[kc] + (unsigned)(q * 128))
                              ^ (unsigned)(((q + kwv[kc]) & 3) << 1);
                a = *(const short8*)(Araw + (gi << 3));
            }
            short8 bfv = *(const short8*)(Bc + boff[kc]);
            acc[q] = __builtin_amdgcn_mfma_f32_16x16x32_bf16(a, bfv, acc[q], 0, 0, 0);
        }
        if (q + 3 < TW) issue(q + 3);
        if (q + 1 < TW) {
            writeB(q + 1, B_lds + ((q + 1) & 1) * BBUF_ELEMS);
            __syncthreads();
        }
    }

    // ---- epilogue: lane owns (b_out = mt*16+fq*4+r, o = nt*16+fr),
    //      TW consecutive floats along ow (8B-aligned f32x2 stores)
    const int o = nt * 16 + fr;
    #pragma unroll
    for (int r = 0; r < 4; ++r) {
        float* dst = out + ((size_t)((mt * 16 + fq * 4 + r) * OUTC + o)) * POUT
                         + (size_t)oh * OWD + ow0;
        #pragma unroll
        for (int j = 0; j < TW / 2; ++j) {
            f32x2 v = { acc[2 * j][r], acc[2 * j + 1][r] };
            *(f32x2*)(dst + 2 * j) = v;
        }
    }
}

__global__ __launch_bounds__(512, 4) void localconv_kernel(
    const float* __restrict__ inp,
    const float* __restrict__ wgt,
    float* __restrict__ out)
{
    extern __shared__ unsigned short smem[];
    unsigned short* Araw  = smem;
    unsigned short* B_lds = smem + AR_ELEMS;

    // bijective chunked XCD swizzle: 682 blocks -> XCD 0,1 get 86, rest 85;
    // within an XCD, l is contiguous (strips of a row share the XCD's L2).
    const int bid = blockIdx.x;
    const int xcd = bid & 7, i = bid >> 3;
    const int l   = (xcd < 2) ? xcd * 86 + i : 172 + (xcd - 2) * 85 + i;
    const int oh    = l / 11;
    const int strip = l % 11;

    if (strip < 10) conv_body<6>(inp, wgt, out, oh, strip * 6, Araw, B_lds);
    else            conv_body<2>(inp, wgt, out, oh, 60, Araw, B_lds);
}

extern "C" void kernel_launch(void* const* d_in, const int* in_sizes, int n_in,
                              void* d_out, int out_size, void* d_ws, size_t ws_size,
                              hipStream_t stream) {
    const float* inp = (const float*)d_in[0];
    const float* wgt = (const float*)d_in[1];
    float* out = (float*)d_out;
    hipFuncSetAttribute((const void*)localconv_kernel,
                        hipFuncAttributeMaxDynamicSharedMemorySize, SMEM_BYTES);
    localconv_kernel<<<dim3(682), 512, SMEM_BYTES, stream>>>(inp, wgt, out);
}